// Round 3
// baseline (84.051 us; speedup 1.0000x reference)
//
#include <hip/hip_runtime.h>
#include <stdint.h>

#define NT 4096
#define L2E 1.44269504f

typedef short s16x8 __attribute__((ext_vector_type(8)));
typedef short s16x4 __attribute__((ext_vector_type(4)));
typedef float f32x16 __attribute__((ext_vector_type(16)));
typedef float f32x4 __attribute__((ext_vector_type(4)));

__device__ __forceinline__ unsigned short f2bf(float f) {
  unsigned int u = __float_as_uint(f);
  u = u + 0x7FFFu + ((u >> 16) & 1u);   // RNE to bf16
  return (unsigned short)(u >> 16);
}

// ============================================================================
// Projection: [wv(128); wq(16); wk(16)*log2e] @ x -> vws[b][c][n] (bf16),
// qws/kws[b][n][16] (bf16, transposed for attn fragments). Grid 256 = b x nt64.
// ============================================================================
__global__ __launch_bounds__(256) void proj_kern(
    const float* __restrict__ x,
    const float* __restrict__ wq, const float* __restrict__ bq,
    const float* __restrict__ wk, const float* __restrict__ bk,
    const float* __restrict__ wv, const float* __restrict__ bv,
    short* __restrict__ qws, short* __restrict__ kws, short* __restrict__ vws) {
  __shared__ __align__(16) unsigned short w_s[160 * 128];  // swizzled rows

  int t = threadIdx.x;
  int blk = blockIdx.x;
  int b = blk >> 6;
  int n0 = (blk & 63) * 64;

  // stage weights, float4 loads, swizzle byte-in-row ^= (row&7)<<4
  for (int idx4 = t; idx4 < 4096; idx4 += 256) {
    int c = idx4 >> 5, ka = (idx4 & 31) * 4;
    f32x4 v = *(const f32x4*)(wv + idx4 * 4);
    s16x4 o; o[0]=(short)f2bf(v[0]); o[1]=(short)f2bf(v[1]); o[2]=(short)f2bf(v[2]); o[3]=(short)f2bf(v[3]);
    unsigned byt = ((unsigned)(ka * 2)) ^ (((unsigned)c & 7u) << 4);
    *(s16x4*)((char*)w_s + c * 256 + byt) = o;
  }
  for (int idx4 = t; idx4 < 512; idx4 += 256) {
    int c128 = idx4 >> 5, ka = (idx4 & 31) * 4;
    f32x4 vq = *(const f32x4*)(wq + idx4 * 4);
    f32x4 vk = *(const f32x4*)(wk + idx4 * 4);
    int rq = 128 + c128, rk = 144 + c128;
    s16x4 oq, ok;
#pragma unroll
    for (int j = 0; j < 4; ++j) { oq[j]=(short)f2bf(vq[j]); ok[j]=(short)f2bf(vk[j] * L2E); }
    unsigned bq_ = ((unsigned)(ka * 2)) ^ (((unsigned)rq & 7u) << 4);
    unsigned bk_ = ((unsigned)(ka * 2)) ^ (((unsigned)rk & 7u) << 4);
    *(s16x4*)((char*)w_s + rq * 256 + bq_) = oq;
    *(s16x4*)((char*)w_s + rk * 256 + bk_) = ok;
  }
  __syncthreads();

  int w = t >> 6, lane = t & 63, lc = lane & 31, hi = lane >> 5;
  int cw = w & 1, mh = w >> 1;
  int nn = cw * 32 + lc;
  int mb0 = mh ? 3 : 0;
  int nmb = mh ? 2 : 3;

  f32x16 zf = {0.f,0.f,0.f,0.f,0.f,0.f,0.f,0.f,0.f,0.f,0.f,0.f,0.f,0.f,0.f,0.f};
  f32x16 acc[3]; acc[0] = zf; acc[1] = zf; acc[2] = zf;

#pragma unroll
  for (int kk = 0; kk < 8; ++kk) {
    int kbase = kk * 16 + hi * 8;
    s16x8 xf;
#pragma unroll
    for (int e = 0; e < 8; ++e)
      xf[e] = (short)f2bf(x[((size_t)b * 128 + kbase + e) * NT + n0 + nn]);
    unsigned byt = ((unsigned)(kk * 32 + hi * 16)) ^ (((unsigned)lc & 7u) << 4);
#pragma unroll
    for (int m2 = 0; m2 < 3; ++m2) {
      if (m2 < nmb) {
        int row = (mb0 + m2) * 32 + lc;
        s16x8 af = *(const s16x8*)((const char*)w_s + row * 256 + byt);
        acc[m2] = __builtin_amdgcn_mfma_f32_32x32x16_bf16(af, xf, acc[m2], 0, 0, 0);
      }
    }
  }

  if (mh == 0) {  // c rows 0..95
#pragma unroll
    for (int m2 = 0; m2 < 3; ++m2)
#pragma unroll
      for (int r = 0; r < 16; ++r) {
        int c = m2 * 32 + (r & 3) + 8 * (r >> 2) + 4 * hi;
        vws[((size_t)b * 128 + c) * NT + n0 + nn] = (short)f2bf(acc[m2][r] + bv[c]);
      }
  } else {
#pragma unroll
    for (int r = 0; r < 16; ++r) {  // c rows 96..127
      int c = 96 + (r & 3) + 8 * (r >> 2) + 4 * hi;
      vws[((size_t)b * 128 + c) * NT + n0 + nn] = (short)f2bf(acc[0][r] + bv[c]);
    }
    // q/k rows (acc[1]): r 0..7 -> q, r 8..15 -> k (scaled by log2e)
    size_t nidx = ((size_t)b * NT + n0 + nn) * 16;
    s16x4 q0, q1, k0, k1;
#pragma unroll
    for (int j = 0; j < 4; ++j) {
      q0[j] = (short)f2bf(acc[1][j]      + bq[j + 4 * hi]);
      q1[j] = (short)f2bf(acc[1][j + 4]  + bq[j + 8 + 4 * hi]);
      k0[j] = (short)f2bf((acc[1][j + 8]  + bk[j + 4 * hi]) * L2E);
      k1[j] = (short)f2bf((acc[1][j + 12] + bk[j + 8 + 4 * hi]) * L2E);
    }
    *(s16x4*)(qws + nidx + 4 * hi)     = q0;
    *(s16x4*)(qws + nidx + 8 + 4 * hi) = q1;
    *(s16x4*)(kws + nidx + 4 * hi)     = k0;
    *(s16x4*)(kws + nidx + 8 + 4 * hi) = k1;
  }
}

// ============================================================================
// Flash attention, barrier-free main loop. 8 waves = 4 j-streams x 2 i-subs.
// QK^T swapped (i per-lane softmax); PV^T with V read directly from L2.
// ============================================================================
#define CROW(r) (((r) & 3) + 8 * ((r) >> 2) + 4 * hi)

__global__ __launch_bounds__(512, 2) void attn_mfma(
    const short* __restrict__ qws, const short* __restrict__ kws, const short* __restrict__ vws,
    const float* __restrict__ x, const float* __restrict__ gp, float* __restrict__ out) {
  __shared__ float scr[64 * 129];
  __shared__ float msc[8 * 32];
  __shared__ float lsc[8 * 32];

  int g = blockIdx.x;
  int r7 = g & 7;
  int b = r7 >> 1;
  int it = (g >> 3) * 2 + (r7 & 1);   // 0..63, batch pinned to XCD pair
  int t = threadIdx.x;
  int w = t >> 6, lane = t & 63, lc = lane & 31, hi = lane >> 5;
  int s = w >> 1, isub = w & 1;
  int i0 = it * 64 + isub * 32;
  int jbase = s * 1024;

  const short* qb = qws + (size_t)b * NT * 16;
  const short* kb = kws + (size_t)b * NT * 16;
  const short* vb = vws + (size_t)b * 128 * NT;

  s16x8 qf = *(const s16x8*)(qb + (size_t)(i0 + lc) * 16 + hi * 8);

  f32x16 zf = {0.f,0.f,0.f,0.f,0.f,0.f,0.f,0.f,0.f,0.f,0.f,0.f,0.f,0.f,0.f,0.f};
  f32x16 acc[4]; acc[0] = zf; acc[1] = zf; acc[2] = zf; acc[3] = zf;
  float m_l = -1e30f, l_l = 0.f;

  const short* vrow = vb + (size_t)lc * NT + jbase + hi * 8;
  s16x8 vcur[8], vnx[8];
#pragma unroll
  for (int cb = 0; cb < 4; ++cb)
#pragma unroll
    for (int sl = 0; sl < 2; ++sl)
      vcur[cb * 2 + sl] = *(const s16x8*)(vrow + (size_t)cb * 32 * NT + sl * 16);
  s16x8 kf = *(const s16x8*)(kb + (size_t)(jbase + lc) * 16 + hi * 8);

  for (int st = 0; st < 32; ++st) {
    int jn = (st + 1) & 31;   // wraps at end (harmless extra load)
    const short* vp = vrow + jn * 32;
#pragma unroll
    for (int cb = 0; cb < 4; ++cb)
#pragma unroll
      for (int sl = 0; sl < 2; ++sl)
        vnx[cb * 2 + sl] = *(const s16x8*)(vp + (size_t)cb * 32 * NT + sl * 16);
    s16x8 kn = *(const s16x8*)(kb + (size_t)(jbase + jn * 32 + lc) * 16 + hi * 8);

    // QK^T swapped: e[r] = E[j0+CROW(r)][i0+lc]  (log2 domain)
    f32x16 e = __builtin_amdgcn_mfma_f32_32x32x16_bf16(kf, qf, zf, 0, 0, 0);

    float mt = e[0];
#pragma unroll
    for (int r = 1; r < 16; ++r) mt = fmaxf(mt, e[r]);
    mt = fmaxf(mt, __shfl_xor(mt, 32));
    if (__any(mt > m_l + 8.0f)) {        // defer-rescale
      float mnew = fmaxf(m_l, mt);
      float corr = __builtin_amdgcn_exp2f(m_l - mnew);
      l_l *= corr;
      float cT[16];
#pragma unroll
      for (int r = 0; r < 16; ++r) cT[r] = __shfl(corr, CROW(r));
#pragma unroll
      for (int cb = 0; cb < 4; ++cb)
#pragma unroll
        for (int r = 0; r < 16; ++r) acc[cb][r] *= cT[r];
      m_l = mnew;
    }
    float p[16]; float rs = 0.f;
#pragma unroll
    for (int r = 0; r < 16; ++r) { p[r] = __builtin_amdgcn_exp2f(e[r] - m_l); rs += p[r]; }
    rs += __shfl_xor(rs, 32);
    l_l += rs;

    // pack P to bf16 words, then permlane-swap into PV^T A-fragments
    unsigned w8[8];
#pragma unroll
    for (int m2 = 0; m2 < 8; ++m2)
      asm("v_cvt_pk_bf16_f32 %0, %1, %2" : "=v"(w8[m2]) : "v"(p[2 * m2]), "v"(p[2 * m2 + 1]));
    unsigned a0 = w8[0], b0 = w8[2];
    asm("v_permlane32_swap_b32 %0, %1" : "+v"(a0), "+v"(b0));
    unsigned a1 = w8[1], b1 = w8[3];
    asm("v_permlane32_swap_b32 %0, %1" : "+v"(a1), "+v"(b1));
    unsigned c0 = w8[4], d0 = w8[6];
    asm("v_permlane32_swap_b32 %0, %1" : "+v"(c0), "+v"(d0));
    unsigned c1 = w8[5], d1 = w8[7];
    asm("v_permlane32_swap_b32 %0, %1" : "+v"(c1), "+v"(d1));
    union PW { unsigned u[4]; s16x8 v; } pa0, pa1;
    pa0.u[0] = a0; pa0.u[1] = a1; pa0.u[2] = b0; pa0.u[3] = b1;
    pa1.u[0] = c0; pa1.u[1] = c1; pa1.u[2] = d0; pa1.u[3] = d1;

#pragma unroll
    for (int cb = 0; cb < 4; ++cb)
      acc[cb] = __builtin_amdgcn_mfma_f32_32x32x16_bf16(pa0.v, vcur[cb * 2], acc[cb], 0, 0, 0);
#pragma unroll
    for (int cb = 0; cb < 4; ++cb)
      acc[cb] = __builtin_amdgcn_mfma_f32_32x32x16_bf16(pa1.v, vcur[cb * 2 + 1], acc[cb], 0, 0, 0);

#pragma unroll
    for (int q2 = 0; q2 < 8; ++q2) vcur[q2] = vnx[q2];
    kf = kn;
  }

  // ---- merge 4 j-streams via LDS, transpose, epilogue ----
  if (hi == 0) { msc[(s * 2 + isub) * 32 + lc] = m_l; lsc[(s * 2 + isub) * 32 + lc] = l_l; }
  __syncthreads();
  float M = -1e30f;
#pragma unroll
  for (int s2 = 0; s2 < 4; ++s2) M = fmaxf(M, msc[(s2 * 2 + isub) * 32 + lc]);
  float L = 0.f;
#pragma unroll
  for (int s2 = 0; s2 < 4; ++s2)
    L += lsc[(s2 * 2 + isub) * 32 + lc] * __builtin_amdgcn_exp2f(msc[(s2 * 2 + isub) * 32 + lc] - M);
  float f = __builtin_amdgcn_exp2f(m_l - M) / L;
  float fT[16];
#pragma unroll
  for (int r = 0; r < 16; ++r) fT[r] = __shfl(f, CROW(r));

  if (s == 0) {
#pragma unroll
    for (int cb = 0; cb < 4; ++cb)
#pragma unroll
      for (int r = 0; r < 16; ++r)
        scr[(isub * 32 + CROW(r)) * 129 + cb * 32 + lc] = acc[cb][r] * fT[r];
  }
  __syncthreads();
#pragma unroll
  for (int round = 1; round < 4; ++round) {
    if (s == round) {
#pragma unroll
      for (int cb = 0; cb < 4; ++cb)
#pragma unroll
        for (int r = 0; r < 16; ++r)
          scr[(isub * 32 + CROW(r)) * 129 + cb * 32 + lc] += acc[cb][r] * fT[r];
    }
    __syncthreads();
  }

  float gam = gp[0];
  int c = t >> 2, ig = t & 3;
  const float* xb = x + ((size_t)b * 128 + c) * NT + it * 64 + ig * 16;
  float* ob = out + ((size_t)b * 128 + c) * NT + it * 64 + ig * 16;
#pragma unroll
  for (int q2 = 0; q2 < 4; ++q2) {
    f32x4 xv = *(const f32x4*)(xb + q2 * 4);
    f32x4 ov;
#pragma unroll
    for (int j = 0; j < 4; ++j)
      ov[j] = gam * scr[(ig * 16 + q2 * 4 + j) * 129 + c] + xv[j];
    *(f32x4*)(ob + q2 * 4) = ov;
  }
}

extern "C" void kernel_launch(void* const* d_in, const int* in_sizes, int n_in,
                              void* d_out, int out_size, void* d_ws, size_t ws_size,
                              hipStream_t stream) {
  const float* x     = (const float*)d_in[0];
  const float* wq    = (const float*)d_in[1];
  const float* bq    = (const float*)d_in[2];
  const float* wk    = (const float*)d_in[3];
  const float* bk    = (const float*)d_in[4];
  const float* wv    = (const float*)d_in[5];
  const float* bv    = (const float*)d_in[6];
  const float* gamma = (const float*)d_in[7];
  float* out = (float*)d_out;

  short* qws = (short*)d_ws;                       // 4*4096*16 bf16 = 512 KB
  short* kws = qws + (size_t)4 * NT * 16;          // 512 KB
  short* vws = kws + (size_t)4 * NT * 16;          // 4 MB

  proj_kern<<<256, 256, 0, stream>>>(x, wq, bq, wk, bk, wv, bv, qws, kws, vws);
  attn_mfma<<<256, 512, 0, stream>>>(qws, kws, vws, x, gamma, out);
}

// Round 4
// 56.282 us; speedup vs baseline: 1.4934x; 1.4934x over previous
//
#include <hip/hip_runtime.h>
#include <stdint.h>

#define NT 4096
#define L2E 1.44269504f

typedef short s16x8 __attribute__((ext_vector_type(8)));
typedef short s16x4 __attribute__((ext_vector_type(4)));
typedef float f32x16 __attribute__((ext_vector_type(16)));
typedef float f32x4 __attribute__((ext_vector_type(4)));

__device__ __forceinline__ unsigned short f2bf(float f) {
  unsigned int u = __float_as_uint(f);
  u = u + 0x7FFFu + ((u >> 16) & 1u);   // RNE to bf16
  return (unsigned short)(u >> 16);
}

// pack 16 f32 p-values into two PV B-operand fragments (verified round-2 map)
__device__ __forceinline__ void pack_pa(const float* p, s16x8* pa) {
  unsigned w8[8];
#pragma unroll
  for (int m = 0; m < 8; ++m)
    asm("v_cvt_pk_bf16_f32 %0, %1, %2" : "=v"(w8[m]) : "v"(p[2 * m]), "v"(p[2 * m + 1]));
  unsigned a0 = w8[0], b0 = w8[2]; asm("v_permlane32_swap_b32 %0, %1" : "+v"(a0), "+v"(b0));
  unsigned a1 = w8[1], b1 = w8[3]; asm("v_permlane32_swap_b32 %0, %1" : "+v"(a1), "+v"(b1));
  unsigned c0 = w8[4], d0 = w8[6]; asm("v_permlane32_swap_b32 %0, %1" : "+v"(c0), "+v"(d0));
  unsigned c1 = w8[5], d1 = w8[7]; asm("v_permlane32_swap_b32 %0, %1" : "+v"(c1), "+v"(d1));
  union PW { unsigned u[4]; s16x8 v; } q0, q1;
  q0.u[0] = a0; q0.u[1] = a1; q0.u[2] = b0; q0.u[3] = b1;
  q1.u[0] = c0; q1.u[1] = c1; q1.u[2] = d0; q1.u[3] = d1;
  pa[0] = q0.v; pa[1] = q1.v;
}

// ============================================================================
// Projection: [wv(128); wq(16); wk(16)*log2e] @ x.  grid 256 = b(4) x ntile(64)
// 512 thr = 8 waves: rowblk(0..3) x ncol(0..1); rowblk3 waves also do q/k rows.
// vws: bf16 [b][c][n]; qws/kws: bf16 [b][n][16].
// ============================================================================
__global__ __launch_bounds__(512, 2) void proj_kern(
    const float* __restrict__ x,
    const float* __restrict__ wq, const float* __restrict__ bq,
    const float* __restrict__ wk, const float* __restrict__ bk,
    const float* __restrict__ wv, const float* __restrict__ bv,
    short* __restrict__ qws, short* __restrict__ kws, short* __restrict__ vws) {
  __shared__ __align__(16) unsigned short w_s[160 * 128];  // 40KB, swizzled rows (256B)
  __shared__ __align__(16) unsigned short x_s[128 * 64];   // 16KB [k][n]

  int t = threadIdx.x;
  int blk = blockIdx.x;
  int b = blk >> 6;
  int n0 = (blk & 63) * 64;

  // stage weights (f32x4 loads), swizzle byte-in-row ^= (row&7)<<4
  for (int i4 = t; i4 < 5120; i4 += 512) {
    int row = i4 >> 5, ka = (i4 & 31) * 4;
    f32x4 v;
    float sc = 1.0f;
    if (row < 128)      v = *(const f32x4*)(wv + row * 128 + ka);
    else if (row < 144) v = *(const f32x4*)(wq + (row - 128) * 128 + ka);
    else              { v = *(const f32x4*)(wk + (row - 144) * 128 + ka); sc = L2E; }
    s16x4 o;
#pragma unroll
    for (int j = 0; j < 4; ++j) o[j] = (short)f2bf(v[j] * sc);
    unsigned byt = ((unsigned)(ka * 2)) ^ (((unsigned)row & 7u) << 4);
    *(s16x4*)((char*)w_s + row * 256 + byt) = o;
  }
  // stage x tile [128 k][64 n]
  {
    int cL = t >> 4, nn4 = (t & 15) * 4;
    for (int cc = 0; cc < 128; cc += 32) {
      int c = cc + cL;
      f32x4 v = *(const f32x4*)(x + ((size_t)b * 128 + c) * NT + n0 + nn4);
      s16x4 o;
#pragma unroll
      for (int j = 0; j < 4; ++j) o[j] = (short)f2bf(v[j]);
      *(s16x4*)(x_s + c * 64 + nn4) = o;
    }
  }
  __syncthreads();

  int w = t >> 6, lane = t & 63, lc = lane & 31, hi = lane >> 5;
  int rblk = w >> 1, nc = w & 1;
  int nn = nc * 32 + lc;

  f32x16 zf = {0.f,0.f,0.f,0.f,0.f,0.f,0.f,0.f,0.f,0.f,0.f,0.f,0.f,0.f,0.f,0.f};
  f32x16 acc = zf, acc2 = zf;

#pragma unroll
  for (int kk = 0; kk < 8; ++kk) {
    int kb0 = kk * 16 + hi * 8;
    s16x8 xf;
#pragma unroll
    for (int e = 0; e < 8; ++e) xf[e] = (short)x_s[(kb0 + e) * 64 + nn];
    unsigned byt = ((unsigned)(kk * 32 + hi * 16)) ^ (((unsigned)lc & 7u) << 4);
    s16x8 af = *(const s16x8*)((const char*)w_s + (rblk * 32 + lc) * 256 + byt);
    acc = __builtin_amdgcn_mfma_f32_32x32x16_bf16(af, xf, acc, 0, 0, 0);
    if (rblk == 3) {
      s16x8 af2 = *(const s16x8*)((const char*)w_s + (128 + lc) * 256 + byt);
      acc2 = __builtin_amdgcn_mfma_f32_32x32x16_bf16(af2, xf, acc2, 0, 0, 0);
    }
  }

#pragma unroll
  for (int r = 0; r < 16; ++r) {
    int c = rblk * 32 + (r & 3) + 8 * (r >> 2) + 4 * hi;
    vws[((size_t)b * 128 + c) * NT + n0 + nn] = (short)f2bf(acc[r] + bv[c]);
  }
  if (rblk == 3) {
    size_t nidx = ((size_t)b * NT + n0 + nn) * 16;
    s16x4 q0, q1, k0, k1;
#pragma unroll
    for (int j = 0; j < 4; ++j) {
      q0[j] = (short)f2bf(acc2[j]      + bq[j + 4 * hi]);
      q1[j] = (short)f2bf(acc2[j + 4]  + bq[j + 8 + 4 * hi]);
      k0[j] = (short)f2bf(acc2[j + 8]  + bk[j + 4 * hi] * L2E);
      k1[j] = (short)f2bf(acc2[j + 12] + bk[j + 8 + 4 * hi] * L2E);
    }
    *(s16x4*)(qws + nidx + 4 * hi)     = q0;
    *(s16x4*)(qws + nidx + 8 + 4 * hi) = q1;
    *(s16x4*)(kws + nidx + 4 * hi)     = k0;
    *(s16x4*)(kws + nidx + 8 + 4 * hi) = k1;
  }
}

// ============================================================================
// Flash attention: 8 waves = 4 j-streams x 2 c-halves. Fixed-base softmax
// (p = 2^e, no running max). V staged in LDS [128c][32j] XOR-swizzled tiles,
// double-buffered, reg-staged prefetch. acc = mfma(V_A, P_B): D[c][i].
// ============================================================================
__global__ __launch_bounds__(512, 2) void attn_mfma(
    const short* __restrict__ qws, const short* __restrict__ kws, const short* __restrict__ vws,
    const float* __restrict__ x, const float* __restrict__ gp, float* __restrict__ out) {
  __shared__ __align__(16) unsigned char lds[65536];
  // main loop: 4 streams x 2 bufs x 8KB V tiles
  // post-loop overlay: scr f32[128][66] @0 (33792B); lsc[4][64] @33792; linv[64] @34816

  int g = blockIdx.x;
  int gg = (g & 7) * 32 + (g >> 3);   // XCD swizzle: batch pinned to XCD pair
  int b = gg >> 6;
  int it = gg & 63;
  int t = threadIdx.x;
  int w = t >> 6, lane = t & 63, lc = lane & 31, hi = lane >> 5;
  int s = w & 3, ch = w >> 2;

  const short* qb = qws + (size_t)b * NT * 16;
  const short* kb = kws + (size_t)b * NT * 16;
  const short* vb = vws + (size_t)b * 128 * NT;

  s16x8 qf[2];
  qf[0] = *(const s16x8*)(qb + (size_t)(it * 64 + lc) * 16 + hi * 8);
  qf[1] = *(const s16x8*)(qb + (size_t)(it * 64 + 32 + lc) * 16 + hi * 8);

  unsigned char* vbuf = lds + s * 16384;
  int jt0 = s * 1024;

  // staging geometry: lane covers row c = ch*64 + ro (+r*16), granule gsl
  int ro = lane >> 2;             // 0..15
  int gsl = lane & 3;             // logical 16B granule (8 j's)
  size_t sbase = (size_t)(ch * 64 + ro) * NT + gsl * 8;
  int wbase = (ch * 64 + ro) * 64 + ((gsl ^ (ro & 3)) << 4);

  s16x8 stg[4];
#pragma unroll
  for (int r = 0; r < 4; ++r)
    stg[r] = *(const s16x8*)(vb + sbase + (size_t)r * 16 * NT + jt0);
#pragma unroll
  for (int r = 0; r < 4; ++r)
    *(s16x8*)(vbuf + wbase + r * 1024) = stg[r];
  s16x8 kf = *(const s16x8*)(kb + (size_t)(jt0 + lc) * 16 + hi * 8);
  __syncthreads();

  f32x16 zf = {0.f,0.f,0.f,0.f,0.f,0.f,0.f,0.f,0.f,0.f,0.f,0.f,0.f,0.f,0.f,0.f};
  f32x16 acc[2][2];
  acc[0][0] = zf; acc[0][1] = zf; acc[1][0] = zf; acc[1][1] = zf;
  float lsum0 = 0.f, lsum1 = 0.f;

  for (int st = 0; st < 32; ++st) {
    unsigned char* cbuf = vbuf + (st & 1) * 8192;
    if (st < 31) {   // T14: issue next-tile loads early
      size_t sj = sbase + (size_t)(jt0 + (st + 1) * 32);
#pragma unroll
      for (int r = 0; r < 4; ++r)
        stg[r] = *(const s16x8*)(vb + sj + (size_t)r * 16 * NT);
    }
    s16x8 kn = kf;
    if (st < 31)
      kn = *(const s16x8*)(kb + (size_t)(jt0 + (st + 1) * 32 + lc) * 16 + hi * 8);

    // QK^T swapped, exp2 domain (K pre-scaled by log2e)
    f32x16 e0 = __builtin_amdgcn_mfma_f32_32x32x16_bf16(kf, qf[0], zf, 0, 0, 0);
    f32x16 e1 = __builtin_amdgcn_mfma_f32_32x32x16_bf16(kf, qf[1], zf, 0, 0, 0);

    float p0[16], p1[16];
#pragma unroll
    for (int r = 0; r < 16; ++r) { p0[r] = __builtin_amdgcn_exp2f(e0[r]); p1[r] = __builtin_amdgcn_exp2f(e1[r]); }
    float a0 = 0.f, a1 = 0.f;
#pragma unroll
    for (int r = 0; r < 16; ++r) { a0 += p0[r]; a1 += p1[r]; }
    lsum0 += a0; lsum1 += a1;

    s16x8 pa0[2], pa1[2];
    pack_pa(p0, pa0);
    pack_pa(p1, pa1);

    // PV: A = V rows c (LDS), B = P; acc D[c][i]
#pragma unroll
    for (int sl = 0; sl < 2; ++sl) {
      int gA = sl * 2 + hi;
#pragma unroll
      for (int cbi = 0; cbi < 2; ++cbi) {
        int c = (ch * 2 + cbi) * 32 + lc;
        s16x8 vf = *(const s16x8*)(cbuf + c * 64 + (((gA ^ (lc & 3))) << 4));
        acc[0][cbi] = __builtin_amdgcn_mfma_f32_32x32x16_bf16(vf, pa0[sl], acc[0][cbi], 0, 0, 0);
        acc[1][cbi] = __builtin_amdgcn_mfma_f32_32x32x16_bf16(vf, pa1[sl], acc[1][cbi], 0, 0, 0);
      }
    }

    if (st < 31) {   // write prefetched tile, one barrier per step
      unsigned char* nbuf = vbuf + ((st & 1) ^ 1) * 8192;
#pragma unroll
      for (int r = 0; r < 4; ++r)
        *(s16x8*)(nbuf + wbase + r * 1024) = stg[r];
    }
    kf = kn;
    __syncthreads();
  }

  // ---- merge streams ----
  float lf0 = lsum0 + __shfl_xor(lsum0, 32);
  float lf1 = lsum1 + __shfl_xor(lsum1, 32);
  float* scr  = (float*)lds;
  float* lsc  = (float*)(lds + 33792);
  float* linv = (float*)(lds + 34816);
  if (ch == 0 && hi == 0) { lsc[s * 64 + lc] = lf0; lsc[s * 64 + 32 + lc] = lf1; }
  __syncthreads();
  if (t < 64) {
    float L = lsc[t] + lsc[64 + t] + lsc[128 + t] + lsc[192 + t];
    linv[t] = 1.0f / L;
  }
#pragma unroll
  for (int rnd = 0; rnd < 4; ++rnd) {
    if (s == rnd) {
#pragma unroll
      for (int isub = 0; isub < 2; ++isub)
#pragma unroll
        for (int cbi = 0; cbi < 2; ++cbi)
#pragma unroll
          for (int r = 0; r < 16; ++r) {
            int crow = (ch * 2 + cbi) * 32 + (r & 3) + 8 * (r >> 2) + 4 * hi;
            int icol = isub * 32 + lc;
            float v = (isub == 0) ? acc[0][cbi][r] : acc[1][cbi][r];
            if (rnd == 0) scr[crow * 66 + icol] = v;
            else          scr[crow * 66 + icol] += v;
          }
    }
    __syncthreads();
  }

  // ---- epilogue: o = gamma * (sum pV)/L + x ----
  float gam = gp[0];
  int cc = t >> 2, iq = t & 3;
  const float* xb = x + ((size_t)b * 128 + cc) * NT + it * 64 + iq * 16;
  float* ob = out + ((size_t)b * 128 + cc) * NT + it * 64 + iq * 16;
#pragma unroll
  for (int q2 = 0; q2 < 4; ++q2) {
    f32x4 xv = *(const f32x4*)(xb + q2 * 4);
    f32x4 ov;
#pragma unroll
    for (int j = 0; j < 4; ++j) {
      int i = iq * 16 + q2 * 4 + j;
      ov[j] = gam * scr[cc * 66 + i] * linv[i] + xv[j];
    }
    *(f32x4*)(ob + q2 * 4) = ov;
  }
}

extern "C" void kernel_launch(void* const* d_in, const int* in_sizes, int n_in,
                              void* d_out, int out_size, void* d_ws, size_t ws_size,
                              hipStream_t stream) {
  const float* x     = (const float*)d_in[0];
  const float* wq    = (const float*)d_in[1];
  const float* bq    = (const float*)d_in[2];
  const float* wk    = (const float*)d_in[3];
  const float* bk    = (const float*)d_in[4];
  const float* wv    = (const float*)d_in[5];
  const float* bv    = (const float*)d_in[6];
  const float* gamma = (const float*)d_in[7];
  float* out = (float*)d_out;

  short* qws = (short*)d_ws;                       // 4*4096*16 bf16 = 512 KB
  short* kws = qws + (size_t)4 * NT * 16;          // 512 KB
  short* vws = kws + (size_t)4 * NT * 16;          // 4 MB

  proj_kern<<<256, 512, 0, stream>>>(x, wq, bq, wk, bk, wv, bv, qws, kws, vws);
  attn_mfma<<<256, 512, 0, stream>>>(qws, kws, vws, x, gamma, out);
}

// Round 5
// 43.792 us; speedup vs baseline: 1.9193x; 1.2852x over previous
//
#include <hip/hip_runtime.h>
#include <stdint.h>

#define NT 4096
#define L2E 1.44269504f

typedef short s16x8 __attribute__((ext_vector_type(8)));
typedef short s16x4 __attribute__((ext_vector_type(4)));
typedef float f32x16 __attribute__((ext_vector_type(16)));
typedef float f32x4 __attribute__((ext_vector_type(4)));
typedef float f32x2 __attribute__((ext_vector_type(2)));

__device__ __forceinline__ unsigned short f2bf(float f) {
  unsigned int u = __float_as_uint(f);
  u = u + 0x7FFFu + ((u >> 16) & 1u);   // RNE to bf16
  return (unsigned short)(u >> 16);
}

// pack 16 f32 p-values into two PV B-operand fragments (verified R2/R4 map)
__device__ __forceinline__ void pack_pa(const float* p, s16x8* pa) {
  unsigned w8[8];
#pragma unroll
  for (int m = 0; m < 8; ++m)
    asm("v_cvt_pk_bf16_f32 %0, %1, %2" : "=v"(w8[m]) : "v"(p[2 * m]), "v"(p[2 * m + 1]));
  unsigned a0 = w8[0], b0 = w8[2]; asm("v_permlane32_swap_b32 %0, %1" : "+v"(a0), "+v"(b0));
  unsigned a1 = w8[1], b1 = w8[3]; asm("v_permlane32_swap_b32 %0, %1" : "+v"(a1), "+v"(b1));
  unsigned c0 = w8[4], d0 = w8[6]; asm("v_permlane32_swap_b32 %0, %1" : "+v"(c0), "+v"(d0));
  unsigned c1 = w8[5], d1 = w8[7]; asm("v_permlane32_swap_b32 %0, %1" : "+v"(c1), "+v"(d1));
  union PW { unsigned u[4]; s16x8 v; } q0, q1;
  q0.u[0] = a0; q0.u[1] = a1; q0.u[2] = b0; q0.u[3] = b1;
  q1.u[0] = c0; q1.u[1] = c1; q1.u[2] = d0; q1.u[3] = d1;
  pa[0] = q0.v; pa[1] = q1.v;
}

// merge helpers: region layout f32 [64 i][132 c-padded]
__device__ __forceinline__ void merge_write(float* reg, const f32x16 (&acc)[2][4],
                                            int lc, int hi) {
#pragma unroll
  for (int isub = 0; isub < 2; ++isub)
#pragma unroll
    for (int cb = 0; cb < 4; ++cb)
#pragma unroll
      for (int q = 0; q < 4; ++q) {
        int c0 = 32 * cb + 8 * q + 4 * hi;
        int row = isub * 32 + lc;
        f32x2 a = { acc[isub][cb][q * 4 + 0], acc[isub][cb][q * 4 + 1] };
        f32x2 b2 = { acc[isub][cb][q * 4 + 2], acc[isub][cb][q * 4 + 3] };
        *(f32x2*)(reg + row * 132 + c0) = a;
        *(f32x2*)(reg + row * 132 + c0 + 2) = b2;
      }
}
__device__ __forceinline__ void merge_add(const float* reg, f32x16 (&acc)[2][4],
                                          int lc, int hi) {
#pragma unroll
  for (int isub = 0; isub < 2; ++isub)
#pragma unroll
    for (int cb = 0; cb < 4; ++cb)
#pragma unroll
      for (int q = 0; q < 4; ++q) {
        int c0 = 32 * cb + 8 * q + 4 * hi;
        int row = isub * 32 + lc;
        f32x2 a = *(const f32x2*)(reg + row * 132 + c0);
        f32x2 b2 = *(const f32x2*)(reg + row * 132 + c0 + 2);
        acc[isub][cb][q * 4 + 0] += a[0];
        acc[isub][cb][q * 4 + 1] += a[1];
        acc[isub][cb][q * 4 + 2] += b2[0];
        acc[isub][cb][q * 4 + 3] += b2[1];
      }
}

// ============================================================================
// Projection: [wv(128); wq(16); wk(16)*log2e] @ x.  grid 256 = b(4) x ntile(64)
// ============================================================================
__global__ __launch_bounds__(512, 2) void proj_kern(
    const float* __restrict__ x,
    const float* __restrict__ wq, const float* __restrict__ bq,
    const float* __restrict__ wk, const float* __restrict__ bk,
    const float* __restrict__ wv, const float* __restrict__ bv,
    short* __restrict__ qws, short* __restrict__ kws, short* __restrict__ vws) {
  __shared__ __align__(16) unsigned short w_s[160 * 128];  // 40KB, swizzled rows (256B)
  __shared__ __align__(16) unsigned short x_s[128 * 64];   // 16KB [k][n]

  int t = threadIdx.x;
  int blk = blockIdx.x;
  int b = blk >> 6;
  int n0 = (blk & 63) * 64;

  for (int i4 = t; i4 < 5120; i4 += 512) {
    int row = i4 >> 5, ka = (i4 & 31) * 4;
    f32x4 v;
    float sc = 1.0f;
    if (row < 128)      v = *(const f32x4*)(wv + row * 128 + ka);
    else if (row < 144) v = *(const f32x4*)(wq + (row - 128) * 128 + ka);
    else              { v = *(const f32x4*)(wk + (row - 144) * 128 + ka); sc = L2E; }
    s16x4 o;
#pragma unroll
    for (int j = 0; j < 4; ++j) o[j] = (short)f2bf(v[j] * sc);
    unsigned byt = ((unsigned)(ka * 2)) ^ (((unsigned)row & 7u) << 4);
    *(s16x4*)((char*)w_s + row * 256 + byt) = o;
  }
  {
    int cL = t >> 4, nn4 = (t & 15) * 4;
    for (int cc = 0; cc < 128; cc += 32) {
      int c = cc + cL;
      f32x4 v = *(const f32x4*)(x + ((size_t)b * 128 + c) * NT + n0 + nn4);
      s16x4 o;
#pragma unroll
      for (int j = 0; j < 4; ++j) o[j] = (short)f2bf(v[j]);
      *(s16x4*)(x_s + c * 64 + nn4) = o;
    }
  }
  __syncthreads();

  int w = t >> 6, lane = t & 63, lc = lane & 31, hi = lane >> 5;
  int rblk = w >> 1, nc = w & 1;
  int nn = nc * 32 + lc;

  f32x16 zf = {0.f,0.f,0.f,0.f,0.f,0.f,0.f,0.f,0.f,0.f,0.f,0.f,0.f,0.f,0.f,0.f};
  f32x16 acc = zf, acc2 = zf;

#pragma unroll
  for (int kk = 0; kk < 8; ++kk) {
    int kb0 = kk * 16 + hi * 8;
    s16x8 xf;
#pragma unroll
    for (int e = 0; e < 8; ++e) xf[e] = (short)x_s[(kb0 + e) * 64 + nn];
    unsigned byt = ((unsigned)(kk * 32 + hi * 16)) ^ (((unsigned)lc & 7u) << 4);
    s16x8 af = *(const s16x8*)((const char*)w_s + (rblk * 32 + lc) * 256 + byt);
    acc = __builtin_amdgcn_mfma_f32_32x32x16_bf16(af, xf, acc, 0, 0, 0);
    if (rblk == 3) {
      s16x8 af2 = *(const s16x8*)((const char*)w_s + (128 + lc) * 256 + byt);
      acc2 = __builtin_amdgcn_mfma_f32_32x32x16_bf16(af2, xf, acc2, 0, 0, 0);
    }
  }

#pragma unroll
  for (int r = 0; r < 16; ++r) {
    int c = rblk * 32 + (r & 3) + 8 * (r >> 2) + 4 * hi;
    vws[((size_t)b * 128 + c) * NT + n0 + nn] = (short)f2bf(acc[r] + bv[c]);
  }
  if (rblk == 3) {
    size_t nidx = ((size_t)b * NT + n0 + nn) * 16;
    s16x4 q0, q1, k0, k1;
#pragma unroll
    for (int j = 0; j < 4; ++j) {
      q0[j] = (short)f2bf(acc2[j]      + bq[j + 4 * hi]);
      q1[j] = (short)f2bf(acc2[j + 4]  + bq[j + 8 + 4 * hi]);
      k0[j] = (short)f2bf(acc2[j + 8]  + bk[j + 4 * hi] * L2E);
      k1[j] = (short)f2bf(acc2[j + 12] + bk[j + 8 + 4 * hi] * L2E);
    }
    *(s16x4*)(qws + nidx + 4 * hi)     = q0;
    *(s16x4*)(qws + nidx + 8 + 4 * hi) = q1;
    *(s16x4*)(kws + nidx + 4 * hi)     = k0;
    *(s16x4*)(kws + nidx + 8 + 4 * hi) = k1;
  }
}

// ============================================================================
// Flash attention: 8 waves = 8 PRIVATE j-streams (512 j each). No barriers in
// the main loop; each wave single-buffers its own 8KB V tile in private LDS.
// Fixed-base softmax (p = 2^e). acc = mfma(V_A, P_B): D[c][i].
// ============================================================================
__global__ __launch_bounds__(512, 2) void attn_mfma(
    const short* __restrict__ qws, const short* __restrict__ kws, const short* __restrict__ vws,
    const float* __restrict__ x, const float* __restrict__ gp, float* __restrict__ out) {
  __shared__ __align__(16) unsigned char lds[69888];
  // loop: 8 x 8KB private V tiles @ [0,65536)
  // merge overlay: rg0 @0, rg1 @33792 (f32[64][132]); lsc @67584 (8*64 f32); linv @69632

  int g = blockIdx.x;
  int gg = (g & 7) * 32 + (g >> 3);   // XCD swizzle: batch pinned to XCD pair
  int b = gg >> 6;
  int it = gg & 63;
  int t = threadIdx.x;
  int w = t >> 6, lane = t & 63, lc = lane & 31, hi = lane >> 5;
  int jt0 = w * 512;

  const short* qb = qws + (size_t)b * NT * 16;
  const short* kb = kws + (size_t)b * NT * 16;
  const short* vb = vws + (size_t)b * 128 * NT;

  s16x8 qf0 = *(const s16x8*)(qb + (size_t)(it * 64 + lc) * 16 + hi * 8);
  s16x8 qf1 = *(const s16x8*)(qb + (size_t)(it * 64 + 32 + lc) * 16 + hi * 8);

  unsigned char* tile = lds + w * 8192;
  int ro = lane >> 2, gsl = lane & 3;
  const short* vsrc = vb + (size_t)ro * NT + gsl * 8 + jt0;
  int woff = ro * 64 + ((gsl ^ (ro & 3)) << 4);

  // prologue: stage tile 0 (wave-private, no barrier)
  s16x8 stg[8];
#pragma unroll
  for (int rr = 0; rr < 8; ++rr)
    stg[rr] = *(const s16x8*)(vsrc + (size_t)rr * 16 * NT);
#pragma unroll
  for (int rr = 0; rr < 8; ++rr)
    *(s16x8*)(tile + rr * 1024 + woff) = stg[rr];
  s16x8 kf = *(const s16x8*)(kb + (size_t)(jt0 + lc) * 16 + hi * 8);

  f32x16 zf = {0.f,0.f,0.f,0.f,0.f,0.f,0.f,0.f,0.f,0.f,0.f,0.f,0.f,0.f,0.f,0.f};
  f32x16 acc[2][4];
#pragma unroll
  for (int i = 0; i < 2; ++i)
#pragma unroll
    for (int j = 0; j < 4; ++j) acc[i][j] = zf;
  float lsum0 = 0.f, lsum1 = 0.f;

  for (int st = 0; st < 16; ++st) {
    s16x8 kn = kf;
    if (st < 15) {   // T14: issue next-tile global loads early
      const short* vp = vsrc + (st + 1) * 32;
#pragma unroll
      for (int rr = 0; rr < 8; ++rr)
        stg[rr] = *(const s16x8*)(vp + (size_t)rr * 16 * NT);
      kn = *(const s16x8*)(kb + (size_t)(jt0 + (st + 1) * 32 + lc) * 16 + hi * 8);
    }

    // QK^T swapped, exp2 domain: e[r] = E[j0+CROW(r)][i0+isub*32+lc]
    f32x16 e0 = __builtin_amdgcn_mfma_f32_32x32x16_bf16(kf, qf0, zf, 0, 0, 0);
    f32x16 e1 = __builtin_amdgcn_mfma_f32_32x32x16_bf16(kf, qf1, zf, 0, 0, 0);

    float p0[16], p1[16];
#pragma unroll
    for (int r = 0; r < 16; ++r) { p0[r] = __builtin_amdgcn_exp2f(e0[r]); p1[r] = __builtin_amdgcn_exp2f(e1[r]); }
    float a0 = 0.f, a1 = 0.f;
#pragma unroll
    for (int r = 0; r < 16; ++r) { a0 += p0[r]; a1 += p1[r]; }
    lsum0 += a0; lsum1 += a1;

    s16x8 pa0[2], pa1[2];
    pack_pa(p0, pa0);
    pack_pa(p1, pa1);

    // PV: A = V rows c (private LDS), B = P; acc D[c][i]
#pragma unroll
    for (int sl = 0; sl < 2; ++sl) {
      int gx = 2 * sl + hi;
#pragma unroll
      for (int cb = 0; cb < 4; ++cb) {
        s16x8 vf = *(const s16x8*)(tile + (cb * 32 + lc) * 64 + ((gx ^ (lc & 3)) << 4));
        acc[0][cb] = __builtin_amdgcn_mfma_f32_32x32x16_bf16(vf, pa0[sl], acc[0][cb], 0, 0, 0);
        acc[1][cb] = __builtin_amdgcn_mfma_f32_32x32x16_bf16(vf, pa1[sl], acc[1][cb], 0, 0, 0);
      }
    }

    if (st < 15) {   // write prefetched tile (after this step's reads; in-order DS)
#pragma unroll
      for (int rr = 0; rr < 8; ++rr)
        *(s16x8*)(tile + rr * 1024 + woff) = stg[rr];
    }
    kf = kn;
  }

  // ---- merge 8 private streams (log tree, 2 scratch regions) ----
  float* rg0  = (float*)lds;
  float* rg1  = (float*)(lds + 33792);
  float* lsc  = (float*)(lds + 67584);
  float* linv = (float*)(lds + 69632);

  float lf0 = lsum0 + __shfl_xor(lsum0, 32);
  float lf1 = lsum1 + __shfl_xor(lsum1, 32);
  if (hi == 0) { lsc[w * 64 + lc] = lf0; lsc[w * 64 + 32 + lc] = lf1; }
  __syncthreads();                                   // S1: loop + lsc done
  if (t < 64) {
    float L = 0.f;
#pragma unroll
    for (int w2 = 0; w2 < 8; ++w2) L += lsc[w2 * 64 + t];
    linv[t] = 1.0f / L;
  }
  if (w == 4) merge_write(rg0, acc, lc, hi);
  if (w == 5) merge_write(rg1, acc, lc, hi);
  __syncthreads();                                   // S2
  if (w == 0) merge_add(rg0, acc, lc, hi);           // {0,4}
  if (w == 1) merge_add(rg1, acc, lc, hi);           // {1,5}
  __syncthreads();                                   // S3 (reads done)
  if (w == 6) merge_write(rg0, acc, lc, hi);
  if (w == 7) merge_write(rg1, acc, lc, hi);
  __syncthreads();                                   // S4
  if (w == 2) merge_add(rg0, acc, lc, hi);           // {2,6}
  if (w == 3) merge_add(rg1, acc, lc, hi);           // {3,7}
  __syncthreads();                                   // S5
  if (w == 2) merge_write(rg0, acc, lc, hi);
  if (w == 3) merge_write(rg1, acc, lc, hi);
  __syncthreads();                                   // S6
  if (w == 0) merge_add(rg0, acc, lc, hi);           // {0,4,2,6}
  if (w == 1) merge_add(rg1, acc, lc, hi);           // {1,5,3,7}
  __syncthreads();                                   // S7
  if (w == 1) merge_write(rg0, acc, lc, hi);
  __syncthreads();                                   // S8
  if (w == 0) {
    merge_add(rg0, acc, lc, hi);                     // all 8
    float li0 = linv[lc], li1 = linv[32 + lc];
#pragma unroll
    for (int cb = 0; cb < 4; ++cb)
#pragma unroll
      for (int r = 0; r < 16; ++r) { acc[0][cb][r] *= li0; acc[1][cb][r] *= li1; }
    merge_write(rg0, acc, lc, hi);                   // final normalized D
  }
  __syncthreads();                                   // S9

  // ---- epilogue: o = gamma * D + x ----
  float gam = gp[0];
  int cc = t >> 2, iq = t & 3;
  const float* xb = x + ((size_t)b * 128 + cc) * NT + it * 64 + iq * 16;
  float* ob = out + ((size_t)b * 128 + cc) * NT + it * 64 + iq * 16;
#pragma unroll
  for (int q2 = 0; q2 < 4; ++q2) {
    f32x4 xv = *(const f32x4*)(xb + q2 * 4);
    f32x4 ov;
#pragma unroll
    for (int j = 0; j < 4; ++j) {
      int i = iq * 16 + q2 * 4 + j;
      ov[j] = gam * rg0[i * 132 + cc] + xv[j];
    }
    *(f32x4*)(ob + q2 * 4) = ov;
  }
}

extern "C" void kernel_launch(void* const* d_in, const int* in_sizes, int n_in,
                              void* d_out, int out_size, void* d_ws, size_t ws_size,
                              hipStream_t stream) {
  const float* x     = (const float*)d_in[0];
  const float* wq    = (const float*)d_in[1];
  const float* bq    = (const float*)d_in[2];
  const float* wk    = (const float*)d_in[3];
  const float* bk    = (const float*)d_in[4];
  const float* wv    = (const float*)d_in[5];
  const float* bv    = (const float*)d_in[6];
  const float* gamma = (const float*)d_in[7];
  float* out = (float*)d_out;

  short* qws = (short*)d_ws;                       // 4*4096*16 bf16 = 512 KB
  short* kws = qws + (size_t)4 * NT * 16;          // 512 KB
  short* vws = kws + (size_t)4 * NT * 16;          // 4 MB

  proj_kern<<<256, 512, 0, stream>>>(x, wq, bq, wk, bk, wv, bv, qws, kws, vws);
  attn_mfma<<<256, 512, 0, stream>>>(qws, kws, vws, x, gamma, out);
}

// Round 6
// 43.538 us; speedup vs baseline: 1.9305x; 1.0058x over previous
//
#include <hip/hip_runtime.h>
#include <stdint.h>

#define NT 4096
#define L2E 1.44269504f

typedef short s16x8 __attribute__((ext_vector_type(8)));
typedef short s16x4 __attribute__((ext_vector_type(4)));
typedef float f32x16 __attribute__((ext_vector_type(16)));
typedef float f32x4 __attribute__((ext_vector_type(4)));

__device__ __forceinline__ unsigned short f2bf(float f) {
  unsigned int u = __float_as_uint(f);
  u = u + 0x7FFFu + ((u >> 16) & 1u);   // RNE to bf16
  return (unsigned short)(u >> 16);
}

// pack 16 f32 p-values into two P fragments (verified R2/R4/R5 map).
// A- and B-fragments share the lane->(outer,k) map on 32x32x16, so these
// serve directly as the PV A-operand.
__device__ __forceinline__ void pack_pa(const float* p, s16x8* pa) {
  unsigned w8[8];
#pragma unroll
  for (int m = 0; m < 8; ++m)
    asm("v_cvt_pk_bf16_f32 %0, %1, %2" : "=v"(w8[m]) : "v"(p[2 * m]), "v"(p[2 * m + 1]));
  unsigned a0 = w8[0], b0 = w8[2]; asm("v_permlane32_swap_b32 %0, %1" : "+v"(a0), "+v"(b0));
  unsigned a1 = w8[1], b1 = w8[3]; asm("v_permlane32_swap_b32 %0, %1" : "+v"(a1), "+v"(b1));
  unsigned c0 = w8[4], d0 = w8[6]; asm("v_permlane32_swap_b32 %0, %1" : "+v"(c0), "+v"(d0));
  unsigned c1 = w8[5], d1 = w8[7]; asm("v_permlane32_swap_b32 %0, %1" : "+v"(c1), "+v"(d1));
  union PW { unsigned u[4]; s16x8 v; } q0, q1;
  q0.u[0] = a0; q0.u[1] = a1; q0.u[2] = b0; q0.u[3] = b1;
  q1.u[0] = c0; q1.u[1] = c1; q1.u[2] = d0; q1.u[3] = d1;
  pa[0] = q0.v; pa[1] = q1.v;
}

// merge helpers; scr layout f32 [64 i][132 c-padded].
// element: i = isub*32 + (r&3)+8*(r>>2)+4*hi ; c = cb*32 + lc
__device__ __forceinline__ void merge_write(float* scr, const f32x16 (&acc)[2][4],
                                            int lc, int hi) {
#pragma unroll
  for (int isub = 0; isub < 2; ++isub)
#pragma unroll
    for (int cb = 0; cb < 4; ++cb)
#pragma unroll
      for (int r = 0; r < 16; ++r) {
        int i = isub * 32 + (r & 3) + 8 * (r >> 2) + 4 * hi;
        scr[i * 132 + cb * 32 + lc] = acc[isub][cb][r];
      }
}
__device__ __forceinline__ void merge_add(const float* scr, f32x16 (&acc)[2][4],
                                          int lc, int hi) {
#pragma unroll
  for (int isub = 0; isub < 2; ++isub)
#pragma unroll
    for (int cb = 0; cb < 4; ++cb)
#pragma unroll
      for (int r = 0; r < 16; ++r) {
        int i = isub * 32 + (r & 3) + 8 * (r >> 2) + 4 * hi;
        acc[isub][cb][r] += scr[i * 132 + cb * 32 + lc];
      }
}

// ============================================================================
// Projection: [wv(128); wq(16); wk(16)*log2e] @ x. grid 256 = b(4) x ntile64.
// Outputs: qws/kws bf16 [b][n][16]; vfrag bf16 [b][jt=n/16][c][hi][8j]
// (V pre-blocked into MFMA B-fragment granules; transposed via LDS).
// ============================================================================
__global__ __launch_bounds__(512, 2) void proj_kern(
    const float* __restrict__ x,
    const float* __restrict__ wq, const float* __restrict__ bq,
    const float* __restrict__ wk, const float* __restrict__ bk,
    const float* __restrict__ wv, const float* __restrict__ bv,
    short* __restrict__ qws, short* __restrict__ kws, short* __restrict__ vfrag) {
  __shared__ __align__(16) unsigned short w_s[160 * 128];  // 40960B, swizzled rows (256B)
  __shared__ __align__(16) unsigned short xv_s[128 * 72];  // 18432B: x tile (stride 64) then V^T scratch (stride 72)

  int t = threadIdx.x;
  int blk = blockIdx.x;
  int b = blk >> 6;
  int n0 = (blk & 63) * 64;

  for (int i4 = t; i4 < 5120; i4 += 512) {
    int row = i4 >> 5, ka = (i4 & 31) * 4;
    f32x4 v;
    float sc = 1.0f;
    if (row < 128)      v = *(const f32x4*)(wv + row * 128 + ka);
    else if (row < 144) v = *(const f32x4*)(wq + (row - 128) * 128 + ka);
    else              { v = *(const f32x4*)(wk + (row - 144) * 128 + ka); sc = L2E; }
    s16x4 o;
#pragma unroll
    for (int j = 0; j < 4; ++j) o[j] = (short)f2bf(v[j] * sc);
    unsigned byt = ((unsigned)(ka * 2)) ^ (((unsigned)row & 7u) << 4);
    *(s16x4*)((char*)w_s + row * 256 + byt) = o;
  }
  {
    int cL = t >> 4, nn4 = (t & 15) * 4;
    for (int cc = 0; cc < 128; cc += 32) {
      int c = cc + cL;
      f32x4 v = *(const f32x4*)(x + ((size_t)b * 128 + c) * NT + n0 + nn4);
      s16x4 o;
#pragma unroll
      for (int j = 0; j < 4; ++j) o[j] = (short)f2bf(v[j]);
      *(s16x4*)(xv_s + c * 64 + nn4) = o;
    }
  }
  __syncthreads();

  int w = t >> 6, lane = t & 63, lc = lane & 31, hi = lane >> 5;
  int rblk = w >> 1, nc = w & 1;
  int nn = nc * 32 + lc;

  f32x16 zf = {0.f,0.f,0.f,0.f,0.f,0.f,0.f,0.f,0.f,0.f,0.f,0.f,0.f,0.f,0.f,0.f};
  f32x16 acc = zf, acc2 = zf;

#pragma unroll
  for (int kk = 0; kk < 8; ++kk) {
    int kb0 = kk * 16 + hi * 8;
    s16x8 xf;
#pragma unroll
    for (int e = 0; e < 8; ++e) xf[e] = (short)xv_s[(kb0 + e) * 64 + nn];
    unsigned byt = ((unsigned)(kk * 32 + hi * 16)) ^ (((unsigned)lc & 7u) << 4);
    s16x8 af = *(const s16x8*)((const char*)w_s + (rblk * 32 + lc) * 256 + byt);
    acc = __builtin_amdgcn_mfma_f32_32x32x16_bf16(af, xf, acc, 0, 0, 0);
    if (rblk == 3) {
      s16x8 af2 = *(const s16x8*)((const char*)w_s + (128 + lc) * 256 + byt);
      acc2 = __builtin_amdgcn_mfma_f32_32x32x16_bf16(af2, xf, acc2, 0, 0, 0);
    }
  }

  // q/k store (no LDS dependency)
  if (rblk == 3) {
    size_t nidx = ((size_t)b * NT + n0 + nn) * 16;
    s16x4 q0, q1, k0, k1;
#pragma unroll
    for (int j = 0; j < 4; ++j) {
      q0[j] = (short)f2bf(acc2[j]      + bq[j + 4 * hi]);
      q1[j] = (short)f2bf(acc2[j + 4]  + bq[j + 8 + 4 * hi]);
      k0[j] = (short)f2bf(acc2[j + 8]  + bk[j + 4 * hi] * L2E);
      k1[j] = (short)f2bf(acc2[j + 12] + bk[j + 8 + 4 * hi] * L2E);
    }
    *(s16x4*)(qws + nidx + 4 * hi)     = q0;
    *(s16x4*)(qws + nidx + 8 + 4 * hi) = q1;
    *(s16x4*)(kws + nidx + 4 * hi)     = k0;
    *(s16x4*)(kws + nidx + 8 + 4 * hi) = k1;
  }

  __syncthreads();   // all xv_s (x-tile) reads done
  // write V bf16 into xv_s, stride 72 (144B rows -> 8 distinct bank bases)
#pragma unroll
  for (int r = 0; r < 16; ++r) {
    int c = rblk * 32 + (r & 3) + 8 * (r >> 2) + 4 * hi;
    xv_s[c * 72 + nn] = f2bf(acc[r] + bv[c]);
  }
  __syncthreads();
  // granule transpose store: vfrag[(b*256 + jt)*128 + c] granule hi2
#pragma unroll
  for (int p = 0; p < 2; ++p) {
    int gid = t + p * 512;
    int c = gid & 127, ng = gid >> 7;        // ng 0..7 = (jtl<<1)|hi2
    s16x8 v = *(const s16x8*)(xv_s + c * 72 + ng * 8);
    size_t idx = (((size_t)b * 256 + (n0 >> 4) + (ng >> 1)) * 128 + c) * 16 + (ng & 1) * 8;
    *(s16x8*)(vfrag + idx) = v;
  }
}

// ============================================================================
// Flash attention: 8 waves = 8 PRIVATE j-streams (512 j each). NO LDS and NO
// barriers in the main loop; V fragments are coalesced 16B global loads from
// vfrag (L2-resident). Fixed-base softmax (p = 2^e). acc = mfma(P_A, V_B):
// D[i][c] (col = c = lane).
// ============================================================================
__global__ __launch_bounds__(512, 2) void attn_mfma(
    const short* __restrict__ qws, const short* __restrict__ kws, const short* __restrict__ vfrag,
    const float* __restrict__ x, const float* __restrict__ gp, float* __restrict__ out) {
  __shared__ __align__(16) unsigned char lds[69888];
  // rg0 @0 (33792B), rg1 @33792 (f32[64][132]); lsc @67584 (8*64 f32); linv @69632

  int g = blockIdx.x;
  int gg = (g & 7) * 32 + (g >> 3);   // XCD swizzle: batch pinned to XCD pair
  int b = gg >> 6;
  int it = gg & 63;
  int t = threadIdx.x;
  int w = t >> 6, lane = t & 63, lc = lane & 31, hi = lane >> 5;
  int jt0 = w * 512;

  const short* qb = qws + (size_t)b * NT * 16;
  const short* kb = kws + (size_t)b * NT * 16;
  const short* vfb = vfrag + (size_t)b * 256 * 128 * 16;

  s16x8 qf0 = *(const s16x8*)(qb + (size_t)(it * 64 + lc) * 16 + hi * 8);
  s16x8 qf1 = *(const s16x8*)(qb + (size_t)(it * 64 + 32 + lc) * 16 + hi * 8);

  f32x16 zf = {0.f,0.f,0.f,0.f,0.f,0.f,0.f,0.f,0.f,0.f,0.f,0.f,0.f,0.f,0.f,0.f};
  f32x16 acc[2][4];
#pragma unroll
  for (int i = 0; i < 2; ++i)
#pragma unroll
    for (int j = 0; j < 4; ++j) acc[i][j] = zf;
  float lsum0 = 0.f, lsum1 = 0.f;

  s16x8 kf = *(const s16x8*)(kb + (size_t)(jt0 + lc) * 16 + hi * 8);

  for (int st = 0; st < 16; ++st) {
    int jtb = (jt0 >> 4) + st * 2;
    // V fragments: coalesced 16B/lane loads (2KB/wave/instr), L2-hit
    s16x8 vB[2][4];
#pragma unroll
    for (int sl = 0; sl < 2; ++sl)
#pragma unroll
      for (int cb = 0; cb < 4; ++cb)
        vB[sl][cb] = *(const s16x8*)(vfb + ((size_t)(jtb + sl) * 128 + cb * 32 + lc) * 16 + hi * 8);
    s16x8 kn = kf;
    if (st < 15)
      kn = *(const s16x8*)(kb + (size_t)(jt0 + (st + 1) * 32 + lc) * 16 + hi * 8);

    // QK^T swapped, exp2 domain: e[r] = E[j = jstep + crow(r,hi)][i0 + lc]
    f32x16 e0 = __builtin_amdgcn_mfma_f32_32x32x16_bf16(kf, qf0, zf, 0, 0, 0);
    f32x16 e1 = __builtin_amdgcn_mfma_f32_32x32x16_bf16(kf, qf1, zf, 0, 0, 0);

    float p0[16], p1[16];
#pragma unroll
    for (int r = 0; r < 16; ++r) { p0[r] = __builtin_amdgcn_exp2f(e0[r]); p1[r] = __builtin_amdgcn_exp2f(e1[r]); }
    float a0 = 0.f, a1 = 0.f;
#pragma unroll
    for (int r = 0; r < 16; ++r) { a0 += p0[r]; a1 += p1[r]; }
    lsum0 += a0; lsum1 += a1;

    s16x8 pa0[2], pa1[2];
    pack_pa(p0, pa0);
    pack_pa(p1, pa1);

    // PV: acc[isub][cb] += P_A x V_B  -> D[i][c]
#pragma unroll
    for (int sl = 0; sl < 2; ++sl)
#pragma unroll
      for (int cb = 0; cb < 4; ++cb) {
        acc[0][cb] = __builtin_amdgcn_mfma_f32_32x32x16_bf16(pa0[sl], vB[sl][cb], acc[0][cb], 0, 0, 0);
        acc[1][cb] = __builtin_amdgcn_mfma_f32_32x32x16_bf16(pa1[sl], vB[sl][cb], acc[1][cb], 0, 0, 0);
      }
    kf = kn;
  }

  // ---- merge 8 private streams (log tree, 2 scratch regions) ----
  float* rg0  = (float*)lds;
  float* rg1  = (float*)(lds + 33792);
  float* lsc  = (float*)(lds + 67584);
  float* linv = (float*)(lds + 69632);

  float lf0 = lsum0 + __shfl_xor(lsum0, 32);
  float lf1 = lsum1 + __shfl_xor(lsum1, 32);
  if (hi == 0) { lsc[w * 64 + lc] = lf0; lsc[w * 64 + 32 + lc] = lf1; }
  __syncthreads();                                   // S1
  if (t < 64) {
    float L = 0.f;
#pragma unroll
    for (int w2 = 0; w2 < 8; ++w2) L += lsc[w2 * 64 + t];
    linv[t] = 1.0f / L;
  }
  if (w == 4) merge_write(rg0, acc, lc, hi);
  if (w == 5) merge_write(rg1, acc, lc, hi);
  __syncthreads();                                   // S2
  if (w == 0) merge_add(rg0, acc, lc, hi);           // {0,4}
  if (w == 1) merge_add(rg1, acc, lc, hi);           // {1,5}
  __syncthreads();                                   // S3
  if (w == 6) merge_write(rg0, acc, lc, hi);
  if (w == 7) merge_write(rg1, acc, lc, hi);
  __syncthreads();                                   // S4
  if (w == 2) merge_add(rg0, acc, lc, hi);           // {2,6}
  if (w == 3) merge_add(rg1, acc, lc, hi);           // {3,7}
  __syncthreads();                                   // S5
  if (w == 2) merge_write(rg0, acc, lc, hi);
  if (w == 3) merge_write(rg1, acc, lc, hi);
  __syncthreads();                                   // S6
  if (w == 0) merge_add(rg0, acc, lc, hi);           // {0,4,2,6}
  if (w == 1) merge_add(rg1, acc, lc, hi);           // {1,5,3,7}
  __syncthreads();                                   // S7
  if (w == 1) merge_write(rg0, acc, lc, hi);
  __syncthreads();                                   // S8
  if (w == 0) {
    merge_add(rg0, acc, lc, hi);                     // all 8 (raw sums)
    merge_write(rg0, acc, lc, hi);
  }
  __syncthreads();                                   // S9

  // ---- epilogue: o = gamma * D/L + x ----
  float gam = gp[0];
  int cc = t >> 2, iq = t & 3;
  const float* xb = x + ((size_t)b * 128 + cc) * NT + it * 64 + iq * 16;
  float* ob = out + ((size_t)b * 128 + cc) * NT + it * 64 + iq * 16;
#pragma unroll
  for (int q2 = 0; q2 < 4; ++q2) {
    f32x4 xv = *(const f32x4*)(xb + q2 * 4);
    f32x4 ov;
#pragma unroll
    for (int j = 0; j < 4; ++j) {
      int i = iq * 16 + q2 * 4 + j;
      ov[j] = gam * rg0[i * 132 + cc] * linv[i] + xv[j];
    }
    *(f32x4*)(ob + q2 * 4) = ov;
  }
}

extern "C" void kernel_launch(void* const* d_in, const int* in_sizes, int n_in,
                              void* d_out, int out_size, void* d_ws, size_t ws_size,
                              hipStream_t stream) {
  const float* x     = (const float*)d_in[0];
  const float* wq    = (const float*)d_in[1];
  const float* bq    = (const float*)d_in[2];
  const float* wk    = (const float*)d_in[3];
  const float* bk    = (const float*)d_in[4];
  const float* wv    = (const float*)d_in[5];
  const float* bv    = (const float*)d_in[6];
  const float* gamma = (const float*)d_in[7];
  float* out = (float*)d_out;

  short* qws   = (short*)d_ws;                       // 4*4096*16 bf16 = 512 KB
  short* kws   = qws + (size_t)4 * NT * 16;          // 512 KB
  short* vfrag = kws + (size_t)4 * NT * 16;          // 4*256*128*16 bf16 = 4 MB

  proj_kern<<<256, 512, 0, stream>>>(x, wq, bq, wk, bk, wv, bv, qws, kws, vfrag);
  attn_mfma<<<256, 512, 0, stream>>>(qws, kws, vfrag, x, gamma, out);
}